// Round 6
// baseline (342.633 us; speedup 1.0000x reference)
//
#include <hip/hip_runtime.h>

#define TSTEPS 365
#define BGRID  20000
#define NMUL   4
#define NEARZERO 1e-6f
#define C    4              // steps per chunk (smaller: V=4 body ~17KB, I-cache + VGPR)
#define NCH  (TSTEPS / C)   // 91 full chunks
#define TAIL (TSTEPS - NCH * C)  // 1
#define V    4              // all 4 cells of one b per thread -> 4 indep chains

struct F3 { float p, t, pet; };   // 12B, innermost (.,3) layout
typedef float f4v __attribute__((ext_vector_type(4)));  // I/O packing only — math stays scalar

// raw transcendentals: bare v_log_f32 / v_exp_f32 (domain: log in >= 1e-6,
// exp2 in [-120, 0] — all normal, no guard codegen).
__device__ __forceinline__ float fast_log2(float x) { return __builtin_amdgcn_logf(x); }
__device__ __forceinline__ float fast_exp2(float x) { return __builtin_amdgcn_exp2f(x); }

__device__ __forceinline__ f4v ld4(const float* p, int i) {
    return *reinterpret_cast<const f4v*>(p + i);     // i = 4*b -> 16B aligned
}

// Phase-separated chunk pipeline (round 2 structure, kept):
//   LOAD(next chunk) ; STORE(prev chunk results) ; COMPUTE(current chunk)
#define LOAD_CHUNK(BUF, N)                                                  \
    _Pragma("unroll")                                                       \
    for (int j_ = 0; j_ < (N); ++j_) { BUF[j_] = *fp; fp += BGRID; }

#define STORE_CHUNK(QS, N)                                                  \
    _Pragma("unroll")                                                       \
    for (int j_ = 0; j_ < (N); ++j_) {                                      \
        *qf = QS[j_]; qf += BGRID;        /* one dwordx4: the whole b row */ \
        *qa = (((QS[j_].x + QS[j_].y) + (QS[j_].z + QS[j_].w))) * 0.25f;    \
        qa += BGRID;                                                        \
    }

#define COMPUTE_CHUNK(BUF, QO, N)                                           \
    _Pragma("unroll")                                                       \
    for (int j_ = 0; j_ < (N); ++j_) { step(BUF[j_], QO[j_]); }

// thread = b. Four independent scalar chains (k=0..3) interleaved by the
// scheduler: measured dependent-issue latency ~10-11 cyc (r0: 1 chain = 11.6
// cyc/inst; r5: 2 chains = 5.3); 4 chains give an 8-cyc same-chain gap ->
// cadence approaches the 2-cyc issue floor. DO NOT pk-pack (r4: -30%).
// waves_per_eu(1,1): 0.31 waves/SIMD supplied; full 512-VGPR budget for RA.
__global__ __launch_bounds__(64) __attribute__((amdgpu_waves_per_eu(1, 1)))
void hbv_fwd(
    const float* __restrict__ forcing,   // (T, B, 3)
    const float* __restrict__ pBETA,  const float* __restrict__ pFC,
    const float* __restrict__ pK0,    const float* __restrict__ pK1,
    const float* __restrict__ pK2,    const float* __restrict__ pLP,
    const float* __restrict__ pPERC,  const float* __restrict__ pUZL,
    const float* __restrict__ pTT,    const float* __restrict__ pCFMAX,
    const float* __restrict__ pCFR,   const float* __restrict__ pCWH,
    const float* __restrict__ pBETAET,const float* __restrict__ pC,
    float* __restrict__ out_avg,         // (T, B)
    float* __restrict__ out_q)           // (T, B, NMUL)
{
    const int b = blockIdx.x * 64 + threadIdx.x;     // grid 313 -> 20032 threads
    if (b >= BGRID) return;
    const int c0 = b * 4;

    const f4v vBETA   = ld4(pBETA, c0);
    const f4v vFC     = ld4(pFC, c0);
    const f4v vK0     = ld4(pK0, c0);
    const f4v vK1     = ld4(pK1, c0);
    const f4v vK2     = ld4(pK2, c0);
    const f4v vLP     = ld4(pLP, c0);
    const f4v vPERC   = ld4(pPERC, c0);
    const f4v vUZL    = ld4(pUZL, c0);
    const f4v vTT     = ld4(pTT, c0);
    const f4v vCFMAX  = ld4(pCFMAX, c0);
    const f4v vCFR    = ld4(pCFR, c0);
    const f4v vCWH    = ld4(pCWH, c0);
    const f4v vBETAET = ld4(pBETAET, c0);
    const f4v vC      = ld4(pC, c0);

    float parBETA[V], parFC[V], parK0[V], parK1[V], parK2[V], parPERC[V],
          parUZL[V], parTT[V], parCFMAX[V], parCWH[V], parBETAET[V], parC[V],
          refreeze_coef[V], inv_FC[V], inv_LPFC[V];
#pragma unroll
    for (int v = 0; v < V; ++v) {
        parBETA[v]   = vBETA[v];   parFC[v]   = vFC[v];
        parK0[v]     = vK0[v];     parK1[v]   = vK1[v];
        parK2[v]     = vK2[v];     parPERC[v] = vPERC[v];
        parUZL[v]    = vUZL[v];    parTT[v]   = vTT[v];
        parCFMAX[v]  = vCFMAX[v];  parCWH[v]  = vCWH[v];
        parBETAET[v] = vBETAET[v]; parC[v]    = vC[v];
        refreeze_coef[v] = vCFR[v] * parCFMAX[v];
        inv_FC[v]   = 1.0f / parFC[v];
        inv_LPFC[v] = 1.0f / (vLP[v] * parFC[v]);
    }

    float snow[V], melt[V], sm[V], suz[V], slz[V];
#pragma unroll
    for (int v = 0; v < V; ++v) {
        snow[v] = NEARZERO; melt[v] = 0.0f; sm[v] = 0.0f; suz[v] = 0.0f; slz[v] = 0.0f;
    }

    // walked 64-bit pointers, shared by all four chains
    const F3* __restrict__ fp = (const F3*)forcing + b;     // stride BGRID per t
    f4v* __restrict__ qf = (f4v*)(out_q + c0);               // stride BGRID f4v per t
    float* __restrict__ qa = out_avg + b;                    // stride BGRID

    auto step = [&](const F3 fv, f4v &qo) {
        float q[V];
#pragma unroll
        for (int v = 0; v < V; ++v) {
            // ---- snow module ----
            const float td = fv.t - parTT[v];
            const float rain    = td > 0.0f ? fv.p : 0.0f;
            const float snow_in = fv.p - rain;
            float snow1 = snow[v] + snow_in;
            const float pot_melt = parCFMAX[v] * fmaxf(td, 0.0f);
            const float melt_amt = fminf(pot_melt, snow1);
            snow1 -= melt_amt;
            float melt1 = melt[v] + melt_amt;
            const float pot_rfz = refreeze_coef[v] * fmaxf(-td, 0.0f);
            const float rfz = fminf(pot_rfz, melt1);
            snow[v] = snow1 + rfz;
            melt1 -= rfz;
            const float tosoil = fmaxf(fmaf(-parCWH[v], snow[v], melt1), 0.0f);
            melt[v] = melt1 - tosoil;

            // ---- soil module (strength-reduced, r5) ----
            const float x1 = fmaxf(sm[v] * inv_FC[v], NEARZERO);
            const float soil_wet = fminf(fast_exp2(parBETA[v] * fast_log2(x1)), 1.0f);
            const float rt = rain + tosoil;
            const float recharge = rt * soil_wet;
            const float sm1 = (sm[v] + rt) - recharge;
            const float sm2 = fminf(sm1, parFC[v]);      // == sm1 - excess
            const float excess = sm1 - sm2;              // off-path, feeds suz
            const float x2 = __builtin_amdgcn_fmed3f(sm2 * inv_LPFC[v], NEARZERO, 1.0f);
            const float ef = fminf(fast_exp2(parBETAET[v] * fast_log2(x2)), 1.0f);
            // sm_ae = max(sm2 - pet*ef, eps)  (etact elimination)
            const float sm_ae = fmaxf(fmaf(-fv.pet, ef, sm2), NEARZERO);
            // omr = max(1 - sm_ae*invFC, 0)
            const float omr = fmaxf(fmaf(-inv_FC[v], sm_ae, 1.0f), 0.0f);
            const float cslz = parC[v] * slz[v];         // prev-step slz: off-path
            const float cap = fminf(slz[v], cslz * omr);
            sm[v] = fmaxf(sm_ae + cap, NEARZERO);
            const float slz_ac = fmaxf(slz[v] - cap, NEARZERO);

            // ---- response routine ----
            const float suz1 = (suz[v] + recharge) + excess;
            const float suz2 = fmaxf(suz1 - parPERC[v], 0.0f);
            const float perc = suz1 - suz2;              // off-path, feeds slz
            const float slz1 = slz_ac + perc;
            const float q0 = parK0[v] * fmaxf(suz2 - parUZL[v], 0.0f);
            const float suz3 = suz2 - q0;
            const float q1 = parK1[v] * suz3;
            suz[v] = fmaf(-parK1[v], suz3, suz3);        // suz3 - q1, fused
            const float q2 = parK2[v] * slz1;
            slz[v] = fmaf(-parK2[v], slz1, slz1);        // slz1 - q2, fused
            q[v] = (q0 + q1) + q2;
        }
        f4v r; r.x = q[0]; r.y = q[1]; r.z = q[2]; r.w = q[3];
        qo = r;
    };

    // ---- software pipeline over 91 full chunks + 1-step tail ----------------
    F3 fA[C], fB[C];
    f4v qA[C], qB[C];

    LOAD_CHUNK(fA, C);                 // ch0 -> fA
    LOAD_CHUNK(fB, C);                 // ch1
    COMPUTE_CHUNK(fA, qA, C);          // ch0

    // chunks as A/B pairs (static buffer parity -> no runtime indexing)
#pragma clang loop unroll(disable)
    for (int p = 0; p < 44; ++p) {
        LOAD_CHUNK(fA, C);             // ch 2p+2
        STORE_CHUNK(qA, C);            // results of ch 2p
        COMPUTE_CHUNK(fB, qB, C);      // ch 2p+1
        LOAD_CHUNK(fB, C);             // ch 2p+3
        STORE_CHUNK(qB, C);            // results of ch 2p+1
        COMPUTE_CHUNK(fA, qA, C);      // ch 2p+2
    }
    // here: qA = ch88, fB = ch89; stored through ch87
    LOAD_CHUNK(fA, C);                 // ch90
    STORE_CHUNK(qA, C);                // ch88
    COMPUTE_CHUNK(fB, qB, C);          // ch89
    LOAD_CHUNK(fB, TAIL);              // ch91 (1 step: t=364)
    STORE_CHUNK(qB, C);                // ch89
    COMPUTE_CHUNK(fA, qA, C);          // ch90
    STORE_CHUNK(qA, C);                // ch90
    COMPUTE_CHUNK(fB, qB, TAIL);       // ch91
    STORE_CHUNK(qB, TAIL);             // ch91 (s_endpgm drains)
}

extern "C" void kernel_launch(void* const* d_in, const int* in_sizes, int n_in,
                              void* d_out, int out_size, void* d_ws, size_t ws_size,
                              hipStream_t stream) {
    // inputs (fp32): 0 forcing, 1 parBETA, 2 parFC, 3 parK0, 4 parK1, 5 parK2,
    // 6 parLP, 7 parPERC, 8 parUZL, 9 parTT, 10 parCFMAX, 11 parCFR, 12 parCWH,
    // 13 parBETAET, 14 parC
    const float* forcing = (const float*)d_in[0];

    float* out_avg = (float*)d_out;                          // (T, B)
    float* out_q   = out_avg + (size_t)TSTEPS * BGRID;       // (T, B, NMUL)

    const int total = BGRID;             // one thread per b, V=4 cells each
    const int block = 64;                // single-wave workgroups
    const int grid  = (total + block - 1) / block;   // 313 (last wave half-active)
    hbv_fwd<<<grid, block, 0, stream>>>(forcing,
        (const float*)d_in[1], (const float*)d_in[2], (const float*)d_in[3],
        (const float*)d_in[4], (const float*)d_in[5], (const float*)d_in[6],
        (const float*)d_in[7], (const float*)d_in[8], (const float*)d_in[9],
        (const float*)d_in[10], (const float*)d_in[11], (const float*)d_in[12],
        (const float*)d_in[13], (const float*)d_in[14],
        out_avg, out_q);
}